// Round 1
// baseline (88.684 us; speedup 1.0000x reference)
//
#include <hip/hip_runtime.h>
#include <math.h>

#define NB 262144
#define MAXC 13
#define BPB 64                     // batches per block
#define NTH 256
#define CORNERS (BPB * MAXC)       // 832
#define GT_FLOATS (BPB * MAXC * 2) // 1664 (6656 B)
#define OUT_FLOATS (BPB * MAXC * 3)// 2496 (9984 B)

// LDS-staged, fully-coalesced version.
// Phase 1: float4-coalesced load of 64 batches' GT rows into LDS (+ nums/ratio).
// Phase 2: per-corner projected (x,z) computed ONCE per corner into LDS.
//          (lat in [-1.4,-0.2] => sin(lat) bounded away from 0; all 13 slots
//           hold valid random angles, so computing invalid corners is safe.)
// Phase 3: per-(b,j) normal from LDS x/z; stage [ox,0,oz] into LDS out buffer
//          (y is identically 0: all scaled corners share y=-1.6*ratio).
// Phase 4: float4-coalesced store of the 9984 B output slab.
__global__ __launch_bounds__(NTH) void render_normals_kernel(
    const float* __restrict__ gt,          // (NB, MAXC, 2) [lon, lat]
    const int* __restrict__ corner_nums,   // (NB,)
    const float* __restrict__ ratio,       // (NB,)
    float* __restrict__ out)               // (NB, MAXC, 3)
{
    __shared__ __align__(16) float s_buf[OUT_FLOATS]; // gt first, reused for out
    __shared__ float s_x[CORNERS];
    __shared__ float s_z[CORNERS];
    __shared__ float s_hs[BPB];
    __shared__ int   s_nums[BPB];

    const int tid = threadIdx.x;
    const int b0  = blockIdx.x * BPB;

    // ---- Phase 1: coalesced gt load (416 float4 / block) ----
    {
        const float4* src = (const float4*)(gt + (size_t)b0 * (MAXC * 2));
        float4* dst = (float4*)s_buf;
        for (int i = tid; i < GT_FLOATS / 4; i += NTH) dst[i] = src[i];
    }
    if (tid < BPB) {
        s_nums[tid] = corner_nums[b0 + tid];
        s_hs[tid]   = -1.6f * ratio[b0 + tid];
    }
    __syncthreads();

    // ---- Phase 2: per-corner (x,z), each corner computed exactly once ----
    for (int i = tid; i < CORNERS; i += NTH) {
        float2 p = ((const float2*)s_buf)[i];   // (lon, lat), 2-way LDS = free
        int b = i / MAXC;
        float sl = __sinf(p.x), cl = __cosf(p.x);
        float st = __sinf(p.y), ct = __cosf(p.y);
        float k = s_hs[b] * ct * __frcp_rn(st); // hs * cot(lat)
        s_x[i] = k * sl;
        s_z[i] = k * cl;
    }
    __syncthreads();

    // ---- Phase 3: normals into LDS out stage ----
    for (int i = tid; i < CORNERS; i += NTH) {
        int b = i / MAXC;
        int j = i - b * MAXC;
        int nums = s_nums[b];
        float ox = 0.0f, oz = 0.0f;
        if (j <= nums) {
            // j < nums : edge (j -> next);  j == nums : wrap row = edge (0 -> 1)
            int i0 = (j == nums) ? 0 : j;
            int i1 = (j == nums) ? 1 : ((j + 1 == nums) ? 0 : j + 1);
            int base = b * MAXC;
            float dx = s_x[base + i1] - s_x[base + i0];
            float dz = s_z[base + i1] - s_z[base + i0];
            float inv = __frsqrt_rn(dx * dx + dz * dz);
            ox = -dz * inv;
            oz =  dx * inv;
        }
        s_buf[3 * i + 0] = ox;   // stride-3 dwords, odd stride => conflict-light
        s_buf[3 * i + 1] = 0.0f;
        s_buf[3 * i + 2] = oz;
    }
    __syncthreads();

    // ---- Phase 4: coalesced out store (624 float4 / block) ----
    {
        const float4* sv = (const float4*)s_buf;
        float4* o4 = (float4*)(out + (size_t)b0 * (MAXC * 3));
        for (int i = tid; i < OUT_FLOATS / 4; i += NTH) o4[i] = sv[i];
    }
}

extern "C" void kernel_launch(void* const* d_in, const int* in_sizes, int n_in,
                              void* d_out, int out_size, void* d_ws, size_t ws_size,
                              hipStream_t stream) {
    const float* gt    = (const float*)d_in[0];  // GT_up (NB, MAXC, 2) f32
    const int*   nums  = (const int*)d_in[1];    // corner_nums (NB,) i32
    const float* ratio = (const float*)d_in[2];  // up_down_ratio (NB,) f32
    float* out = (float*)d_out;                  // (NB, MAXC, 3) f32

    int grid = NB / BPB;                         // 4096 blocks, 256 threads
    render_normals_kernel<<<grid, NTH, 0, stream>>>(gt, nums, ratio, out);
}